// Round 13
// baseline (133.239 us; speedup 1.0000x reference)
//
#include <hip/hip_runtime.h>
#include <hip/hip_fp16.h>

#define PTAB_STRIDE 64   // halves per row = 128 B

typedef float    f32x4 __attribute__((ext_vector_type(4)));
typedef _Float16 half8 __attribute__((ext_vector_type(8)));
typedef _Float16 h2    __attribute__((ext_vector_type(2)));

__device__ __forceinline__ h2 u2h2(unsigned int u) {
    union { unsigned int u; h2 h; } c; c.u = u; return c.h;
}

__device__ __forceinline__ float fdot2x(h2 a, h2 b, float c) {
#if __has_builtin(__builtin_amdgcn_fdot2)
    return __builtin_amdgcn_fdot2(a, b, c, false);
#else
    return c + (float)a[0] * (float)b[0] + (float)a[1] * (float)b[1];
#endif
}

// DPP permute (VALU pipe, within 16-lane rows). 0xB1=quad xor1,
// 0x4E=quad xor2, 0x141=row_half_mirror (xor7), 0x140=row_mirror (xor15).
#define DPPX(v, ctrl) \
    ((unsigned)__builtin_amdgcn_update_dpp(0, (int)(v), (ctrl), 0xf, 0xf, true))

// 16-lane-row swap: with a==b==p on entry, exit: a=p[l&~16], b=p[l|16].
__device__ __forceinline__ void swap16(unsigned &a, unsigned &b) {
#if __has_builtin(__builtin_amdgcn_permlane16_swap)
    auto rr = __builtin_amdgcn_permlane16_swap(a, b, false, false);
    a = (unsigned)rr[0]; b = (unsigned)rr[1];
#else
    asm volatile("s_nop 1\n\t"
                 "v_permlane16_swap_b32 %0, %1"
                 : "+v"(a), "+v"(b));
#endif
}

// 32-lane-half swap: with a==b==p on entry, exit: a=p[l&~32], b=p[l|32].
__device__ __forceinline__ void swap32(unsigned &a, unsigned &b) {
#if __has_builtin(__builtin_amdgcn_permlane32_swap)
    auto rr = __builtin_amdgcn_permlane32_swap(a, b, false, false);
    a = (unsigned)rr[0]; b = (unsigned)rr[1];
#else
    asm volatile("s_nop 1\n\t"
                 "v_permlane32_swap_b32 %0, %1"
                 : "+v"(a), "+v"(b));
#endif
}

// ---------------------------------------------------------------------------
// Kernel 0: pack B-fragments (W^T, fp16, zero-padded to K=320 x N=64) in the
// exact mfma_f32_16x16x32_f16 per-lane layout, + fused bias table.
// ---------------------------------------------------------------------------
__global__ __launch_bounds__(64) void prep_kernel(
    const float* __restrict__ Wih, const float* __restrict__ bih,
    const float* __restrict__ bhh, __half* __restrict__ Bfrag,
    float* __restrict__ bias64)
{
    const int lane = threadIdx.x;
    const int st   = blockIdx.x;
    if (st == 40) {
        if (lane < 64) bias64[lane] = (lane < 50) ? bih[lane] + bhh[lane] : 0.f;
        return;
    }
    const int s  = st >> 2, t = st & 3;
    const int n  = 16 * t + (lane & 15);
    const int kb = lane >> 4;
    half8 v;
    #pragma unroll
    for (int j = 0; j < 8; ++j) {
        const int k = 32 * s + 8 * kb + j;
        float w = 0.f;
        if (n < 50 && k < 300) w = Wih[n * 300 + k];
        v[j] = (_Float16)w;
    }
    *reinterpret_cast<half8*>(Bfrag + ((size_t)st * 64 + lane) * 8) = v;
}

// ---------------------------------------------------------------------------
// Phase 1: ptab[v][h] = fp16( dot(emb[v,:], W_ih[h,:]) + b_ih + b_hh )
// One wave per 16 vocab rows, 4 N-tile accumulators, 40 MFMAs. (proven)
// ---------------------------------------------------------------------------
__global__ __launch_bounds__(64) void ptab_mfma(
    const float* __restrict__ emb, const __half* __restrict__ Bfrag,
    const float* __restrict__ bias64, __half* __restrict__ ptab)
{
    const int lane = threadIdx.x;
    const int v0   = blockIdx.x * 16;
    const int m    = lane & 15;
    const int kb   = lane >> 4;
    const float* Erow = emb + (size_t)(v0 + m) * 300;
    const half8* BF   = reinterpret_cast<const half8*>(Bfrag);

    f32x4 acc[4];
    #pragma unroll
    for (int t = 0; t < 4; ++t) acc[t] = (f32x4){0.f, 0.f, 0.f, 0.f};

    #pragma unroll
    for (int s = 0; s < 9; ++s) {
        const int k0 = 32 * s + 8 * kb;
        float4 p0 = *(const float4*)(Erow + k0);
        float4 p1 = *(const float4*)(Erow + k0 + 4);
        half8 a;
        a[0] = (_Float16)p0.x; a[1] = (_Float16)p0.y;
        a[2] = (_Float16)p0.z; a[3] = (_Float16)p0.w;
        a[4] = (_Float16)p1.x; a[5] = (_Float16)p1.y;
        a[6] = (_Float16)p1.z; a[7] = (_Float16)p1.w;
        #pragma unroll
        for (int t = 0; t < 4; ++t)
            acc[t] = __builtin_amdgcn_mfma_f32_16x16x32_f16(
                a, BF[(4 * s + t) * 64 + lane], acc[t], 0, 0, 0);
    }
    {   // tail K-step s=9: k = 288..319, valid only k < 300
        half8 a;
        #pragma unroll
        for (int j = 0; j < 8; ++j) {
            const int k = 288 + 8 * kb + j;
            float e = 0.f;
            if (k < 300) e = Erow[k];
            a[j] = (_Float16)e;
        }
        #pragma unroll
        for (int t = 0; t < 4; ++t)
            acc[t] = __builtin_amdgcn_mfma_f32_16x16x32_f16(
                a, BF[(36 + t) * 64 + lane], acc[t], 0, 0, 0);
    }

    const int nn = lane & 15;
    #pragma unroll
    for (int t = 0; t < 4; ++t) {
        const float bt = bias64[16 * t + nn];
        #pragma unroll
        for (int r = 0; r < 4; ++r)
            ptab[(size_t)(v0 + 4 * kb + r) * PTAB_STRIDE + 16 * t + nn] =
                (__half)(acc[t][r] + bt);
    }
}

// ---------------------------------------------------------------------------
// Phase 2: recurrence + head. One sequence per wave, 256 waves (1/CU).
// VALU-only xor all-gather for h:
//   pack(xor1 DPP) -> swap16 -> 2x swap32 gives F0..F3 = p[(l&15)|{0,32,16,48}]
//   then DPP levels xor2/xor7/xor5/xor15/xor13/xor8/xor10 derive the other
//   28 slots. EACH level's 4 dots immediately follow it in source order so
//   the scheduler fills DPP wait-states with dot2 work (r10 lesson: an
//   uninterleaved 28-DPP cascade pays ~2-4 stall cyc per DPP).
// W_hh pre-packed per-lane in slot order -> 32 order-invariant v_dot2_f32_f16.
// Lanes >=50: W=0, x=0 -> h stays exactly 0, never pollutes valid lanes.
// ---------------------------------------------------------------------------
__global__ __launch_bounds__(64, 1) void rnn_kernel(
    const int* __restrict__ tokens, const __half* __restrict__ ptab,
    const float* __restrict__ Whh,
    const float* __restrict__ Wfc, const float* __restrict__ bfc,
    float* __restrict__ out)
{
    __shared__ int stok[544];
    const int lane = threadIdx.x;
    const int b    = blockIdx.x;

    #pragma unroll
    for (int k = 0; k < 8; ++k)
        stok[lane + 64 * k] = tokens[b * 512 + lane + 64 * k];
    if (lane < 32) stok[512 + lane] = 0;     // pad: token 0 -> valid row
    __syncthreads();

    // slot bases (bits 4-5 fixed by the swap family) and deltas (low nibble)
    const int lb = lane & 15;
    const int base[4] = {lb, lb | 32, lb | 16, lb | 48};
    const int dlt[8]  = {0, 2, 7, 5, 15, 13, 8, 10};

    // W_hh row of this lane, packed in exact slot order.
    unsigned wpk[8][4];
    #pragma unroll
    for (int di = 0; di < 8; ++di) {
        #pragma unroll
        for (int f = 0; f < 4; ++f) {
            const int ka = base[f] ^ dlt[di];
            const int kb2 = ka ^ 1;
            _Float16 wa = (lane < 50 && ka < 50)
                              ? (_Float16)Whh[lane * 50 + ka]  : (_Float16)0.f;
            _Float16 wb = (lane < 50 && kb2 < 50)
                              ? (_Float16)Whh[lane * 50 + kb2] : (_Float16)0.f;
            union { h2 h; unsigned u; } c;
            c.h = (h2){wa, wb};
            wpk[di][f] = c.u;
        }
    }

    float h = 0.f;

#define GA(T) ptab[(size_t)(T) * PTAB_STRIDE + lane]

    __half x0 = GA(stok[0]), x1 = GA(stok[1]), x2 = GA(stok[2]), x3 = GA(stok[3]);
    __half x4 = GA(stok[4]), x5 = GA(stok[5]), x6 = GA(stok[6]), x7 = GA(stok[7]);
    int k0 = stok[8],  k1 = stok[9],  k2 = stok[10], k3 = stok[11];
    int k4 = stok[12], k5 = stok[13], k6 = stok[14], k7 = stok[15];

#define DOT4(di, V0, V1, V2, V3)                                             \
        s0 = fdot2x(u2h2(V0), u2h2(wpk[di][0]), s0);                         \
        s1 = fdot2x(u2h2(V1), u2h2(wpk[di][1]), s1);                         \
        s2 = fdot2x(u2h2(V2), u2h2(wpk[di][2]), s2);                         \
        s3 = fdot2x(u2h2(V3), u2h2(wpk[di][3]), s3);

#define RNN_STEP(XV)                                                         \
    {                                                                        \
        union { _Float16 hf; unsigned short us; } hcv;                       \
        hcv.hf = (_Float16)h;                                                \
        unsigned hh = (unsigned)hcv.us;                                      \
        unsigned nbr = DPPX(hh, 0xB1);                /* xor1 */             \
        unsigned p   = hh | (nbr << 16);              /* (h[l], h[l^1]) */   \
        unsigned a16 = p, b16 = p;                                           \
        swap16(a16, b16);                                                    \
        unsigned F0 = a16, F1 = a16; swap32(F0, F1);                         \
        unsigned F2 = b16, F3 = b16; swap32(F2, F3);                         \
        float s0 = 0.f, s1 = 0.f, s2 = 0.f, s3 = 0.f;                        \
        DOT4(0, F0, F1, F2, F3)                       /* d=0  */             \
        unsigned A0 = DPPX(F0, 0x4E), A1 = DPPX(F1, 0x4E);                   \
        unsigned A2 = DPPX(F2, 0x4E), A3 = DPPX(F3, 0x4E);                   \
        DOT4(1, A0, A1, A2, A3)                       /* d=2  */             \
        unsigned B0 = DPPX(F0, 0x141), B1 = DPPX(F1, 0x141);                 \
        unsigned B2 = DPPX(F2, 0x141), B3 = DPPX(F3, 0x141);                 \
        DOT4(2, B0, B1, B2, B3)                       /* d=7  */             \
        unsigned C0 = DPPX(A0, 0x141), C1 = DPPX(A1, 0x141);                 \
        unsigned C2 = DPPX(A2, 0x141), C3 = DPPX(A3, 0x141);                 \
        DOT4(3, C0, C1, C2, C3)                       /* d=5  */             \
        unsigned D0 = DPPX(F0, 0x140), D1 = DPPX(F1, 0x140);                 \
        unsigned D2 = DPPX(F2, 0x140), D3 = DPPX(F3, 0x140);                 \
        DOT4(4, D0, D1, D2, D3)                       /* d=15 */             \
        unsigned E0 = DPPX(A0, 0x140), E1 = DPPX(A1, 0x140);                 \
        unsigned E2 = DPPX(A2, 0x140), E3 = DPPX(A3, 0x140);                 \
        DOT4(5, E0, E1, E2, E3)                       /* d=13 */             \
        unsigned G0 = DPPX(B0, 0x140), G1 = DPPX(B1, 0x140);                 \
        unsigned G2 = DPPX(B2, 0x140), G3 = DPPX(B3, 0x140);                 \
        DOT4(6, G0, G1, G2, G3)                       /* d=8  */             \
        unsigned H0 = DPPX(C0, 0x140), H1 = DPPX(C1, 0x140);                 \
        unsigned H2 = DPPX(C2, 0x140), H3 = DPPX(C3, 0x140);                 \
        DOT4(7, H0, H1, H2, H3)                       /* d=10 */             \
        float aa = (float)(XV) + ((s0 + s1) + (s2 + s3));                    \
        aa = fminf(9.f, fmaxf(-9.f, aa));                                    \
        float ee = __expf(2.f * aa);                                         \
        h = fmaf(-2.f, __builtin_amdgcn_rcpf(ee + 1.f), 1.f);                \
    }

    for (int t = 0; t < 512; t += 8) {
        __half n0 = GA(k0), n1 = GA(k1), n2 = GA(k2), n3 = GA(k3);
        __half n4 = GA(k4), n5 = GA(k5), n6 = GA(k6), n7 = GA(k7);
        k0 = stok[t + 16]; k1 = stok[t + 17]; k2 = stok[t + 18]; k3 = stok[t + 19];
        k4 = stok[t + 20]; k5 = stok[t + 21]; k6 = stok[t + 22]; k7 = stok[t + 23];

        RNN_STEP(x0); RNN_STEP(x1); RNN_STEP(x2); RNN_STEP(x3);
        RNN_STEP(x4); RNN_STEP(x5); RNN_STEP(x6); RNN_STEP(x7);

        x0 = n0; x1 = n1; x2 = n2; x3 = n3;
        x4 = n4; x5 = n5; x6 = n6; x7 = n7;
    }
#undef RNN_STEP
#undef DOT4
#undef GA

    // ---- head: out[b][o] = sum_h h[h] * W_fc[o][h] + b_fc[o] ----
    float hv = (lane < 50) ? h : 0.f;
    #pragma unroll
    for (int o = 0; o < 4; ++o) {
        float w = (lane < 50) ? Wfc[o * 50 + lane] : 0.f;
        float p = hv * w;
        #pragma unroll
        for (int s = 32; s > 0; s >>= 1) p += __shfl_xor(p, s, 64);
        if (lane == 0) out[b * 4 + o] = p + bfc[o];
    }
}

extern "C" void kernel_launch(void* const* d_in, const int* in_sizes, int n_in,
                              void* d_out, int out_size, void* d_ws, size_t ws_size,
                              hipStream_t stream)
{
    const int*   tokens = (const int*)d_in[0];
    const float* emb    = (const float*)d_in[1];
    const float* Wih    = (const float*)d_in[2];
    const float* Whh    = (const float*)d_in[3];
    const float* bih    = (const float*)d_in[4];
    const float* bhh    = (const float*)d_in[5];
    const float* Wfc    = (const float*)d_in[6];
    const float* bfc    = (const float*)d_in[7];

    char* ws = (char*)d_ws;
    __half* ptab   = (__half*)ws;                       // 6,400,000 B
    __half* Bfrag  = (__half*)(ws + 6400000);           //    40,960 B
    float*  bias64 = (float*)(ws + 6440960);            //       256 B
    float*  outp   = (float*)d_out;

    prep_kernel<<<41, 64, 0, stream>>>(Wih, bih, bhh, Bfrag, bias64);
    ptab_mfma<<<3125, 64, 0, stream>>>(emb, Bfrag, bias64, ptab);
    rnn_kernel<<<256, 64, 0, stream>>>(tokens, ptab, Whh, Wfc, bfc, outp);
}

// Round 14
// 114.187 us; speedup vs baseline: 1.1668x; 1.1668x over previous
//
#include <hip/hip_runtime.h>
#include <hip/hip_fp16.h>

#define PTAB_STRIDE 64   // halves per row = 128 B

typedef float    f32x4 __attribute__((ext_vector_type(4)));
typedef _Float16 half8 __attribute__((ext_vector_type(8)));
typedef _Float16 h2    __attribute__((ext_vector_type(2)));

__device__ __forceinline__ h2 u2h2(unsigned int u) {
    union { unsigned int u; h2 h; } c; c.u = u; return c.h;
}

__device__ __forceinline__ float fdot2x(h2 a, h2 b, float c) {
#if __has_builtin(__builtin_amdgcn_fdot2)
    return __builtin_amdgcn_fdot2(a, b, c, false);
#else
    return c + (float)a[0] * (float)b[0] + (float)a[1] * (float)b[1];
#endif
}

__device__ __forceinline__ float clamp9(float a) {
#if __has_builtin(__builtin_amdgcn_fmed3f)
    return __builtin_amdgcn_fmed3f(a, -9.f, 9.f);   // 1 VALU op
#else
    return fminf(9.f, fmaxf(-9.f, a));
#endif
}

// ---------------------------------------------------------------------------
// Kernel 0: pack B-fragments (W^T, fp16, zero-padded to K=320 x N=64) in the
// exact mfma_f32_16x16x32_f16 per-lane layout, + fused bias table.
// ---------------------------------------------------------------------------
__global__ __launch_bounds__(64) void prep_kernel(
    const float* __restrict__ Wih, const float* __restrict__ bih,
    const float* __restrict__ bhh, __half* __restrict__ Bfrag,
    float* __restrict__ bias64)
{
    const int lane = threadIdx.x;
    const int st   = blockIdx.x;
    if (st == 40) {
        if (lane < 64) bias64[lane] = (lane < 50) ? bih[lane] + bhh[lane] : 0.f;
        return;
    }
    const int s  = st >> 2, t = st & 3;
    const int n  = 16 * t + (lane & 15);
    const int kb = lane >> 4;
    half8 v;
    #pragma unroll
    for (int j = 0; j < 8; ++j) {
        const int k = 32 * s + 8 * kb + j;
        float w = 0.f;
        if (n < 50 && k < 300) w = Wih[n * 300 + k];
        v[j] = (_Float16)w;
    }
    *reinterpret_cast<half8*>(Bfrag + ((size_t)st * 64 + lane) * 8) = v;
}

// ---------------------------------------------------------------------------
// Phase 1: ptab[v][h] = fp16( dot(emb[v,:], W_ih[h,:]) + b_ih + b_hh )
// One wave per 16 vocab rows, 4 N-tile accumulators, 40 MFMAs. (proven r8)
// ---------------------------------------------------------------------------
__global__ __launch_bounds__(64) void ptab_mfma(
    const float* __restrict__ emb, const __half* __restrict__ Bfrag,
    const float* __restrict__ bias64, __half* __restrict__ ptab)
{
    const int lane = threadIdx.x;
    const int v0   = blockIdx.x * 16;
    const int m    = lane & 15;
    const int kb   = lane >> 4;
    const float* Erow = emb + (size_t)(v0 + m) * 300;
    const half8* BF   = reinterpret_cast<const half8*>(Bfrag);

    f32x4 acc[4];
    #pragma unroll
    for (int t = 0; t < 4; ++t) acc[t] = (f32x4){0.f, 0.f, 0.f, 0.f};

    #pragma unroll
    for (int s = 0; s < 9; ++s) {
        const int k0 = 32 * s + 8 * kb;
        float4 p0 = *(const float4*)(Erow + k0);
        float4 p1 = *(const float4*)(Erow + k0 + 4);
        half8 a;
        a[0] = (_Float16)p0.x; a[1] = (_Float16)p0.y;
        a[2] = (_Float16)p0.z; a[3] = (_Float16)p0.w;
        a[4] = (_Float16)p1.x; a[5] = (_Float16)p1.y;
        a[6] = (_Float16)p1.z; a[7] = (_Float16)p1.w;
        #pragma unroll
        for (int t = 0; t < 4; ++t)
            acc[t] = __builtin_amdgcn_mfma_f32_16x16x32_f16(
                a, BF[(4 * s + t) * 64 + lane], acc[t], 0, 0, 0);
    }
    {   // tail K-step s=9: k = 288..319, valid only k < 300
        half8 a;
        #pragma unroll
        for (int j = 0; j < 8; ++j) {
            const int k = 288 + 8 * kb + j;
            float e = 0.f;
            if (k < 300) e = Erow[k];
            a[j] = (_Float16)e;
        }
        #pragma unroll
        for (int t = 0; t < 4; ++t)
            acc[t] = __builtin_amdgcn_mfma_f32_16x16x32_f16(
                a, BF[(36 + t) * 64 + lane], acc[t], 0, 0, 0);
    }

    const int nn = lane & 15;
    #pragma unroll
    for (int t = 0; t < 4; ++t) {
        const float bt = bias64[16 * t + nn];
        #pragma unroll
        for (int r = 0; r < 4; ++r)
            ptab[(size_t)(v0 + 4 * kb + r) * PTAB_STRIDE + 16 * t + nn] =
                (__half)(acc[t][r] + bt);
    }
}

// ---------------------------------------------------------------------------
// Phase 2: recurrence + head. One sequence per wave, 256 waves (1/CU).
// r9 structure (best measured: 87.7us / 410 cyc/step): lane l owns h[l];
// per step 1 ds_write_b16 + 6 half8 + 1 h2 uniform-broadcast reads (in-order
// DS pipe; compiler emits fine-grained lgkmcnt so dots start as reads land).
// Changes vs r9 (chain-shortening only):
//   - dot in 4 chains (depth 13 -> 7)
//   - v_med3_f32 single-op clamp in tanh
// ---------------------------------------------------------------------------
__global__ __launch_bounds__(64, 1) void rnn_kernel(
    const int* __restrict__ tokens, const __half* __restrict__ ptab,
    const float* __restrict__ Whh,
    const float* __restrict__ Wfc, const float* __restrict__ bfc,
    float* __restrict__ out)
{
    __shared__ int stok[544];
    __shared__ __align__(16) _Float16 hbuf[64];
    const int lane = threadIdx.x;
    const int b    = blockIdx.x;
    const int hc   = lane < 50 ? lane : 49;

    #pragma unroll
    for (int k = 0; k < 8; ++k)
        stok[lane + 64 * k] = tokens[b * 512 + lane + 64 * k];
    if (lane < 32) stok[512 + lane] = 0;     // pad: token 0 -> valid row
    __syncthreads();

    // W_hh row for this lane: 25 packed fp16 pairs (lane>=50 -> dup of 49;
    // harmless: its h never leaves the lane and its x/W products land in
    // lanes' own h which is ignored by the head).
    unsigned int wh_u[25];
    #pragma unroll
    for (int j = 0; j < 25; ++j) {
        float2 w2 = *(const float2*)(Whh + hc * 50 + 2 * j);
        union { h2 h; unsigned int u; } c;
        c.h = (h2){(_Float16)w2.x, (_Float16)w2.y};
        wh_u[j] = c.u;
    }
    #pragma unroll
    for (int j = 0; j < 25; ++j)
        asm volatile("" : "+v"(wh_u[j]));    // opaque def (r9 behavior)

    float h = 0.f;

#define GA(T) ptab[(size_t)(T) * PTAB_STRIDE + lane]

    __half x0 = GA(stok[0]), x1 = GA(stok[1]), x2 = GA(stok[2]), x3 = GA(stok[3]);
    __half x4 = GA(stok[4]), x5 = GA(stok[5]), x6 = GA(stok[6]), x7 = GA(stok[7]);
    int k0 = stok[8],  k1 = stok[9],  k2 = stok[10], k3 = stok[11];
    int k4 = stok[12], k5 = stok[13], k6 = stok[14], k7 = stok[15];

#define SL(Q, i) __builtin_shufflevector(Q, Q, 2*(i), 2*(i)+1)
#define WH(j) u2h2(wh_u[j])

#define RNN_STEP(XV)                                                         \
    {                                                                        \
        hbuf[lane] = (_Float16)h;          /* ds_write_b16, in-order */      \
        const half8* H8 = (const half8*)hbuf;                                \
        half8 q0 = H8[0], q1 = H8[1], q2 = H8[2];                            \
        half8 q3 = H8[3], q4 = H8[4], q5 = H8[5];                            \
        h2 q6 = *(const h2*)(hbuf + 48);                                     \
        float s0 = 0.f, s1 = 0.f, s2 = 0.f, s3 = 0.f;                        \
        s0 = fdot2x(SL(q0,0), WH(0),  s0); s1 = fdot2x(SL(q0,1), WH(1),  s1);\
        s2 = fdot2x(SL(q0,2), WH(2),  s2); s3 = fdot2x(SL(q0,3), WH(3),  s3);\
        s0 = fdot2x(SL(q1,0), WH(4),  s0); s1 = fdot2x(SL(q1,1), WH(5),  s1);\
        s2 = fdot2x(SL(q1,2), WH(6),  s2); s3 = fdot2x(SL(q1,3), WH(7),  s3);\
        s0 = fdot2x(SL(q2,0), WH(8),  s0); s1 = fdot2x(SL(q2,1), WH(9),  s1);\
        s2 = fdot2x(SL(q2,2), WH(10), s2); s3 = fdot2x(SL(q2,3), WH(11), s3);\
        s0 = fdot2x(SL(q3,0), WH(12), s0); s1 = fdot2x(SL(q3,1), WH(13), s1);\
        s2 = fdot2x(SL(q3,2), WH(14), s2); s3 = fdot2x(SL(q3,3), WH(15), s3);\
        s0 = fdot2x(SL(q4,0), WH(16), s0); s1 = fdot2x(SL(q4,1), WH(17), s1);\
        s2 = fdot2x(SL(q4,2), WH(18), s2); s3 = fdot2x(SL(q4,3), WH(19), s3);\
        s0 = fdot2x(SL(q5,0), WH(20), s0); s1 = fdot2x(SL(q5,1), WH(21), s1);\
        s2 = fdot2x(SL(q5,2), WH(22), s2); s3 = fdot2x(SL(q5,3), WH(23), s3);\
        s0 = fdot2x(q6,       WH(24), s0);                                   \
        float a = ((float)(XV) + (s1 + s3)) + (s0 + s2);                     \
        a = clamp9(a);                                                       \
        float e = __expf(2.f * a);                                           \
        h = fmaf(-2.f, __builtin_amdgcn_rcpf(e + 1.f), 1.f);                 \
    }

    for (int t = 0; t < 512; t += 8) {
        __half n0 = GA(k0), n1 = GA(k1), n2 = GA(k2), n3 = GA(k3);
        __half n4 = GA(k4), n5 = GA(k5), n6 = GA(k6), n7 = GA(k7);
        k0 = stok[t + 16]; k1 = stok[t + 17]; k2 = stok[t + 18]; k3 = stok[t + 19];
        k4 = stok[t + 20]; k5 = stok[t + 21]; k6 = stok[t + 22]; k7 = stok[t + 23];

        RNN_STEP(x0); RNN_STEP(x1); RNN_STEP(x2); RNN_STEP(x3);
        RNN_STEP(x4); RNN_STEP(x5); RNN_STEP(x6); RNN_STEP(x7);

        x0 = n0; x1 = n1; x2 = n2; x3 = n3;
        x4 = n4; x5 = n5; x6 = n6; x7 = n7;
    }
#undef RNN_STEP
#undef SL
#undef WH
#undef GA

    // ---- head: out[b][o] = sum_h h[h] * W_fc[o][h] + b_fc[o] ----
    float hv = (lane < 50) ? h : 0.f;
    #pragma unroll
    for (int o = 0; o < 4; ++o) {
        float w = (lane < 50) ? Wfc[o * 50 + lane] : 0.f;
        float p = hv * w;
        #pragma unroll
        for (int s = 32; s > 0; s >>= 1) p += __shfl_xor(p, s, 64);
        if (lane == 0) out[b * 4 + o] = p + bfc[o];
    }
}

extern "C" void kernel_launch(void* const* d_in, const int* in_sizes, int n_in,
                              void* d_out, int out_size, void* d_ws, size_t ws_size,
                              hipStream_t stream)
{
    const int*   tokens = (const int*)d_in[0];
    const float* emb    = (const float*)d_in[1];
    const float* Wih    = (const float*)d_in[2];
    const float* Whh    = (const float*)d_in[3];
    const float* bih    = (const float*)d_in[4];
    const float* bhh    = (const float*)d_in[5];
    const float* Wfc    = (const float*)d_in[6];
    const float* bfc    = (const float*)d_in[7];

    char* ws = (char*)d_ws;
    __half* ptab   = (__half*)ws;                       // 6,400,000 B
    __half* Bfrag  = (__half*)(ws + 6400000);           //    40,960 B
    float*  bias64 = (float*)(ws + 6440960);            //       256 B
    float*  outp   = (float*)d_out;

    prep_kernel<<<41, 64, 0, stream>>>(Wih, bih, bhh, Bfrag, bias64);
    ptab_mfma<<<3125, 64, 0, stream>>>(emb, Bfrag, bias64, ptab);
    rnn_kernel<<<256, 64, 0, stream>>>(tokens, ptab, Whh, Wfc, bfc, outp);
}